// Round 6
// baseline (89.608 us; speedup 1.0000x reference)
//
#include <hip/hip_runtime.h>

typedef __attribute__((ext_vector_type(8))) short bf16x8;
typedef __attribute__((ext_vector_type(4))) float f32x4;

namespace {
constexpr int NB=8, N1=4096, N2=1024, F1=128, F2=256, H2=256;
constexpr int TM=32;
constexpr float SLOPE=0.2f, EPSD=1e-10f;
constexpr int WS_XYZ=0, WS_W1=131072, WS_W2=327680;
constexpr int XT_STRIDE=784;   // 768B row + 16B pad -> rows rotate 4 banks
constexpr int H_STRIDE=528;    // 512B row + 16B pad
}

__device__ __forceinline__ unsigned short f2bf(float f){
  union{float f; unsigned u;} v; v.f=f;
  unsigned r = v.u + 0x7FFFu + ((v.u>>16)&1u);   // RNE
  return (unsigned short)(r>>16);
}
__device__ __forceinline__ float lrelu(float x){ return x>=0.f? x : SLOPE*x; }

// W1/W2 -> bf16 transposed, MFMA-fragment-linear: frag id = s*16 + nq*4 + nt,
// lane*16B = 8 bf16 along k for (n = nq*64+nt*16+(lane&15), k0 = s*32+(lane>>4)*8).
__global__ __launch_bounds__(256)
void transform_w(const float* __restrict__ W1, const float* __restrict__ W2,
                 const float* __restrict__ xyz2, char* __restrict__ ws)
{
  int id = blockIdx.x*256 + threadIdx.x;
  if (id < 12288) {                       // W1T: 192 frags x 64 lanes
    int frag = id >> 6, ln = id & 63;
    int n = (((frag>>2)&3)*64) + ((frag&3)*16) + (ln & 15);
    int k0 = (frag>>4)*32 + (ln>>4)*8;
    const float* src = W1 + (size_t)k0*256 + n;
    unsigned u[4];
    #pragma unroll
    for (int p=0;p<4;++p)
      u[p] = (unsigned)f2bf(src[(2*p)*256]) | ((unsigned)f2bf(src[(2*p+1)*256])<<16);
    *(uint4*)(ws + WS_W1 + frag*1024 + ln*16) = make_uint4(u[0],u[1],u[2],u[3]);
  } else if (id < 20480) {                // W2T: 128 frags
    id -= 12288;
    int frag = id >> 6, ln = id & 63;
    int n = (((frag>>2)&3)*64) + ((frag&3)*16) + (ln & 15);
    int k0 = (frag>>4)*32 + (ln>>4)*8;
    const float* src = W2 + (size_t)k0*256 + n;
    unsigned u[4];
    #pragma unroll
    for (int p=0;p<4;++p)
      u[p] = (unsigned)f2bf(src[(2*p)*256]) | ((unsigned)f2bf(src[(2*p+1)*256])<<16);
    *(uint4*)(ws + WS_W2 + frag*1024 + ln*16) = make_uint4(u[0],u[1],u[2],u[3]);
  } else if (id < 28672) {                // xyz2q: (x,y,z,|.|^2)
    id -= 20480;
    int bb = id >> 10, j = id & 1023;
    const float* sp = xyz2 + ((size_t)bb*N2 + j)*3;
    float x=sp[0], y=sp[1], z=sp[2];
    *(float4*)(ws + WS_XYZ + ((size_t)bb*1024 + j)*16) =
        make_float4(x,y,z,x*x+y*y+z*z);
  }
}

// TM=32, 256 threads, grid 1024 -> 4 blocks/CU (4 waves/SIMD)
__global__ __launch_bounds__(256, 4)
void fp_mfma(const float* __restrict__ xyz1, const float* __restrict__ p1,
             const float* __restrict__ p2,   const char* __restrict__ ws,
             const float* __restrict__ b1,   const float* __restrict__ b2,
             float* __restrict__ out)
{
  __shared__ __align__(16) char smem[TM*XT_STRIDE];  // 25088: cand 8K -> Xt -> h 16.9K
  __shared__ float s_w[TM][4];
  __shared__ int   s_idx[TM][4];

  const int t = threadIdx.x;
  const int b = blockIdx.x & 7;                // batch == XCD
  const int row0 = (blockIdx.x >> 3) * TM;
  const int lane = t & 63;
  const int lrow = lane & 15, lg = lane >> 4;
  const int nq = t >> 6;                       // wave owns n-quadrant, all 32 m

  // ===== Phase A: 3-NN. 8 threads/row x 128 j each =====
  {
    const float4* x2q = (const float4*)(ws + WS_XYZ + (size_t)b*16384);
    const int row = t >> 3, slice = t & 7;
    const float* x1 = xyz1 + ((size_t)b*N1 + row0 + row)*3;
    const float px=x1[0], py=x1[1], pz=x1[2];
    const float sq1 = px*px + py*py + pz*pz;
    float d0=3.4e38f, d1=3.4e38f, d2=3.4e38f;
    int i0=0, i1=0, i2=0;
    const int j0 = slice*128;
    #pragma unroll 8
    for (int j = j0; j < j0+128; ++j) {
      float4 q = x2q[j];
      float dot = px*q.x + py*q.y + pz*q.z;
      float d = fmaf(-2.f, dot, sq1 + q.w);
      bool c0 = d < d0, c1 = d < d1, c2 = d < d2;
      i2 = c1 ? i1 : (c2 ? j : i2);
      i1 = c0 ? i0 : (c1 ? j : i1);
      i0 = c0 ? j  : i0;
      d2 = __builtin_amdgcn_fmed3f(d, d1, d2);
      d1 = __builtin_amdgcn_fmed3f(d, d0, d1);
      d0 = fminf(d, d0);
    }
    float* cd = (float*)smem + t*8;
    cd[0]=d0; cd[1]=d1; cd[2]=d2;
    ((int*)cd)[4]=i0; ((int*)cd)[5]=i1; ((int*)cd)[6]=i2;
  }
  __syncthreads();
  if (t < TM) {                                // merge 8 slices, j-ascending (ties->ref)
    float d0=3.4e38f,d1=3.4e38f,d2=3.4e38f; int i0=0,i1=0,i2=0;
    for (int p=0;p<8;++p){
      const float* cd = (const float*)smem + (t*8 + p)*8;
      for (int c=0;c<3;++c){
        float d = cd[c]; int ii = ((const int*)cd)[4+c];
        if (d < d2) {
          if (d < d1) { d2=d1; i2=i1;
            if (d < d0) { d1=d0; i1=i0; d0=d; i0=ii; } else { d1=d; i1=ii; }
          } else { d2=d; i2=ii; }
        }
      }
    }
    d0=fmaxf(d0,EPSD); d1=fmaxf(d1,EPSD); d2=fmaxf(d2,EPSD);
    float w0=1.f/d0, w1=1.f/d1, w2=1.f/d2, inv=1.f/(w0+w1+w2);
    s_w[t][0]=w0*inv; s_w[t][1]=w1*inv; s_w[t][2]=w2*inv;
    s_idx[t][0]=i0; s_idx[t][1]=i1; s_idx[t][2]=i2;
  }
  __syncthreads();

  // ===== Phase B =====
  const int rr = t >> 3, qq = t & 7;           // X build: 8 thr/row, 8 k each
  const float w0_=s_w[rr][0], w1_=s_w[rr][1], w2_=s_w[rr][2];
  const int g0=s_idx[rr][0], g1=s_idx[rr][1], g2=s_idx[rr][2];
  const char* wsW1 = ws + WS_W1;
  const char* wsW2 = ws + WS_W2;
  const float* p2b = p2 + (size_t)b*N2*F2;
  const float* p1r = p1 + ((size_t)b*N1 + row0 + rr)*F1;

  auto issueAny = [&](int kcg, float4* g){
    if (kcg < 4) {
      const int k0 = kcg*64 + qq*8;
      const float4* q0 = (const float4*)(p2b + (size_t)g0*F2 + k0);
      const float4* q1 = (const float4*)(p2b + (size_t)g1*F2 + k0);
      const float4* q2 = (const float4*)(p2b + (size_t)g2*F2 + k0);
      g[0]=q0[0]; g[1]=q0[1]; g[2]=q1[0]; g[3]=q1[1]; g[4]=q2[0]; g[5]=q2[1];
    } else {
      const float4* q = (const float4*)(p1r + (kcg*64 + qq*8 - F2));
      g[0]=q[0]; g[1]=q[1];
    }
  };
  auto writeAny = [&](int kcg, const float4* g){
    float v[8];
    if (kcg < 4) {
      #pragma unroll
      for (int p=0;p<2;++p){
        v[4*p+0] = fmaf(w2_, g[4+p].x, fmaf(w1_, g[2+p].x, w0_*g[p].x));
        v[4*p+1] = fmaf(w2_, g[4+p].y, fmaf(w1_, g[2+p].y, w0_*g[p].y));
        v[4*p+2] = fmaf(w2_, g[4+p].z, fmaf(w1_, g[2+p].z, w0_*g[p].z));
        v[4*p+3] = fmaf(w2_, g[4+p].w, fmaf(w1_, g[2+p].w, w0_*g[p].w));
      }
    } else {
      #pragma unroll
      for (int p=0;p<2;++p){
        v[4*p+0]=g[p].x; v[4*p+1]=g[p].y; v[4*p+2]=g[p].z; v[4*p+3]=g[p].w;
      }
    }
    unsigned u[4];
    #pragma unroll
    for (int p=0;p<4;++p)
      u[p] = (unsigned)f2bf(v[2*p]) | ((unsigned)f2bf(v[2*p+1])<<16);
    *(uint4*)(smem + rr*XT_STRIDE + (kcg*8 + qq)*16) = make_uint4(u[0],u[1],u[2],u[3]);
  };
  auto loadW = [&](const char* base, int s, bf16x8* dst){  // coalesced 1KB frags
    #pragma unroll
    for (int nt=0;nt<4;++nt)
      dst[nt] = *(const bf16x8*)(base + ((s*16 + nq*4 + nt)<<10) + lane*16);
  };
  auto gemmStep = [&](int slot4, const bf16x8* bw, f32x4 (&ac)[2][4],
                      const char* Ab, int stride){
    bf16x8 af[2];
    #pragma unroll
    for (int mt=0;mt<2;++mt)
      af[mt] = *(const bf16x8*)(Ab + (mt*16+lrow)*stride + (slot4+lg)*16);
    #pragma unroll
    for (int mt=0;mt<2;++mt)
      #pragma unroll
      for (int nt=0;nt<4;++nt)
        ac[mt][nt] = __builtin_amdgcn_mfma_f32_16x16x32_bf16(af[mt], bw[nt], ac[mt][nt], 0,0,0);
  };

  f32x4 acc[2][4];
  #pragma unroll
  for (int mt=0;mt<2;++mt)
    #pragma unroll
    for (int nt=0;nt<4;++nt) acc[mt][nt] = (f32x4){0.f,0.f,0.f,0.f};

  // ---- build full X tile (32 x 384), depth-2 gather pipeline ----
  float4 ga[6], gb[6];
  issueAny(0, ga); issueAny(1, gb);
  writeAny(0, ga); issueAny(2, ga);
  writeAny(1, gb); issueAny(3, gb);
  writeAny(2, ga); issueAny(4, ga);
  writeAny(3, gb); issueAny(5, gb);
  writeAny(4, ga); writeAny(5, gb);
  bf16x8 bwA[4], bwB[4];
  loadW(wsW1, 0, bwA);
  __syncthreads();

  // ---- GEMM1: 12 K32 steps, no internal barriers, W reg-dbuf ----
  #pragma unroll
  for (int u=0; u<6; ++u) {
    loadW(wsW1, 2*u+1, bwB);
    gemmStep((2*u)*4,   bwA, acc, smem, XT_STRIDE);
    if (u<5) loadW(wsW1, 2*u+2, bwA);
    else     loadW(wsW2, 0, bwA);              // prefetch W2 step 0
    gemmStep((2*u+1)*4, bwB, acc, smem, XT_STRIDE);
  }
  __syncthreads();                             // Xt dead

  // ---- h = lrelu(acc + b1) -> LDS [32][264 shorts] ----
  {
    float bb[4];
    #pragma unroll
    for (int nt=0;nt<4;++nt) bb[nt] = b1[nq*64 + nt*16 + lrow];
    #pragma unroll
    for (int mt=0;mt<2;++mt)
      #pragma unroll
      for (int rg=0;rg<4;++rg) {
        const int row = mt*16 + lg*4 + rg;
        #pragma unroll
        for (int nt=0;nt<4;++nt) {
          const int col = nq*64 + nt*16 + lrow;
          *(short*)(smem + row*H_STRIDE + col*2) =
              (short)f2bf(lrelu(acc[mt][nt][rg] + bb[nt]));
        }
      }
  }
  __syncthreads();

  // ---- GEMM2: h(32x256) @ W2, 8 K32 steps ----
  f32x4 acc2[2][4];
  #pragma unroll
  for (int mt=0;mt<2;++mt)
    #pragma unroll
    for (int nt=0;nt<4;++nt) acc2[mt][nt] = (f32x4){0.f,0.f,0.f,0.f};
  #pragma unroll
  for (int u=0; u<4; ++u) {
    loadW(wsW2, 2*u+1, bwB);
    gemmStep((2*u)*4,   bwA, acc2, smem, H_STRIDE);
    if (u<3) loadW(wsW2, 2*u+2, bwA);
    gemmStep((2*u+1)*4, bwB, acc2, smem, H_STRIDE);
  }

  // ---- epilogue ----
  {
    float bb[4];
    #pragma unroll
    for (int nt=0;nt<4;++nt) bb[nt] = b2[nq*64 + nt*16 + lrow];
    float* ob = out + ((size_t)b*N1 + row0) * H2;
    #pragma unroll
    for (int mt=0;mt<2;++mt)
      #pragma unroll
      for (int rg=0;rg<4;++rg) {
        const int row = mt*16 + lg*4 + rg;
        #pragma unroll
        for (int nt=0;nt<4;++nt) {
          const int col = nq*64 + nt*16 + lrow;
          ob[(size_t)row*H2 + col] = lrelu(acc2[mt][nt][rg] + bb[nt]);
        }
      }
  }
}

extern "C" void kernel_launch(void* const* d_in, const int* in_sizes, int n_in,
                              void* d_out, int out_size, void* d_ws, size_t ws_size,
                              hipStream_t stream) {
  const float* xyz1    = (const float*)d_in[0];
  const float* xyz2    = (const float*)d_in[1];
  const float* points1 = (const float*)d_in[2];
  const float* points2 = (const float*)d_in[3];
  const float* W1      = (const float*)d_in[4];
  const float* b1      = (const float*)d_in[5];
  const float* W2      = (const float*)d_in[6];
  const float* b2      = (const float*)d_in[7];
  float* out = (float*)d_out;

  hipLaunchKernelGGL(transform_w, dim3(112), dim3(256), 0, stream,
                     W1, W2, xyz2, (char*)d_ws);
  hipLaunchKernelGGL(fp_mfma, dim3(NB * (N1 / TM)), dim3(256), 0, stream,
                     xyz1, points1, points2, (const char*)d_ws, b1, b2, out);
}

// Round 7
// 47.199 us; speedup vs baseline: 1.8985x; 1.8985x over previous
//
#include <hip/hip_runtime.h>

typedef __attribute__((ext_vector_type(8))) short bf16x8;
typedef __attribute__((ext_vector_type(4))) float f32x4;

namespace {
constexpr int NB=8, N1=4096, N2=1024, F1=128, F2=256, H2=256;
constexpr int TM=32;
constexpr float SLOPE=0.2f, EPSD=1e-10f;
constexpr int WS_XYZ=0, WS_W1=131072, WS_W2=327680;
constexpr int XT_STRIDE=784;   // 768B row + 16B pad -> rows rotate 4 banks
constexpr int H_STRIDE=528;    // 512B row + 16B pad
}

__device__ __forceinline__ unsigned short f2bf(float f){
  union{float f; unsigned u;} v; v.f=f;
  unsigned r = v.u + 0x7FFFu + ((v.u>>16)&1u);   // RNE
  return (unsigned short)(r>>16);
}
__device__ __forceinline__ float lrelu(float x){ return x>=0.f? x : SLOPE*x; }

// W1/W2 -> bf16 transposed, MFMA-fragment-linear: frag id = s*16 + nq*4 + nt,
// lane*16B = 8 bf16 along k for (n = nq*64+nt*16+(lane&15), k0 = s*32+(lane>>4)*8).
__global__ __launch_bounds__(256)
void transform_w(const float* __restrict__ W1, const float* __restrict__ W2,
                 const float* __restrict__ xyz2, char* __restrict__ ws)
{
  int id = blockIdx.x*256 + threadIdx.x;
  if (id < 12288) {                       // W1T: 192 frags x 64 lanes
    int frag = id >> 6, ln = id & 63;
    int n = (((frag>>2)&3)*64) + ((frag&3)*16) + (ln & 15);
    int k0 = (frag>>4)*32 + (ln>>4)*8;
    const float* src = W1 + (size_t)k0*256 + n;
    unsigned u[4];
    #pragma unroll
    for (int p=0;p<4;++p)
      u[p] = (unsigned)f2bf(src[(2*p)*256]) | ((unsigned)f2bf(src[(2*p+1)*256])<<16);
    *(uint4*)(ws + WS_W1 + frag*1024 + ln*16) = make_uint4(u[0],u[1],u[2],u[3]);
  } else if (id < 20480) {                // W2T: 128 frags
    id -= 12288;
    int frag = id >> 6, ln = id & 63;
    int n = (((frag>>2)&3)*64) + ((frag&3)*16) + (ln & 15);
    int k0 = (frag>>4)*32 + (ln>>4)*8;
    const float* src = W2 + (size_t)k0*256 + n;
    unsigned u[4];
    #pragma unroll
    for (int p=0;p<4;++p)
      u[p] = (unsigned)f2bf(src[(2*p)*256]) | ((unsigned)f2bf(src[(2*p+1)*256])<<16);
    *(uint4*)(ws + WS_W2 + frag*1024 + ln*16) = make_uint4(u[0],u[1],u[2],u[3]);
  } else if (id < 28672) {                // xyz2q: (x,y,z,|.|^2)
    id -= 20480;
    int bb = id >> 10, j = id & 1023;
    const float* sp = xyz2 + ((size_t)bb*N2 + j)*3;
    float x=sp[0], y=sp[1], z=sp[2];
    *(float4*)(ws + WS_XYZ + ((size_t)bb*1024 + j)*16) =
        make_float4(x,y,z,x*x+y*y+z*z);
  }
}

// TM=32, 256 threads, grid 1024. launch_bounds(256,2): do NOT cap VGPRs
// (rounds 4/6: caps of 60/48 VGPR serialized all load pipelines, +60% time).
__global__ __launch_bounds__(256, 2)
void fp_mfma(const float* __restrict__ xyz1, const float* __restrict__ p1,
             const float* __restrict__ p2,   const char* __restrict__ ws,
             const float* __restrict__ b1,   const float* __restrict__ b2,
             float* __restrict__ out)
{
  __shared__ __align__(16) char smem[TM*XT_STRIDE];  // 25088: cand 8K -> Xt -> h 16.9K
  __shared__ float s_w[TM][4];
  __shared__ int   s_idx[TM][4];

  const int t = threadIdx.x;
  const int b = blockIdx.x & 7;                // batch == XCD
  const int row0 = (blockIdx.x >> 3) * TM;
  const int lane = t & 63, wv = t >> 6;
  const int lrow = lane & 15, lg = lane >> 4;
  const int nq = wv;                           // wave owns n-quadrant, all 32 m

  // ===== Phase A: 3-NN. row = lane&31, slice = wv*2 + (lane>>5), 128 j each =====
  {
    const float4* x2q = (const float4*)(ws + WS_XYZ + (size_t)b*16384);
    const int row = lane & 31, slice = wv*2 + (lane >> 5);
    const float* x1 = xyz1 + ((size_t)b*N1 + row0 + row)*3;
    const float px=x1[0], py=x1[1], pz=x1[2];
    const float sq1 = px*px + py*py + pz*pz;
    float d0=3.4e38f, d1=3.4e38f, d2=3.4e38f;
    int i0=0, i1=0, i2=0;
    const int j0 = slice*128;
    #pragma unroll 8
    for (int j = j0; j < j0+128; ++j) {
      float4 q = x2q[j];                       // half-wave-uniform, L2-resident
      float dot = px*q.x + py*q.y + pz*q.z;
      float d = fmaf(-2.f, dot, sq1 + q.w);
      bool c0 = d < d0, c1 = d < d1, c2 = d < d2;
      i2 = c1 ? i1 : (c2 ? j : i2);
      i1 = c0 ? i0 : (c1 ? j : i1);
      i0 = c0 ? j  : i0;
      d2 = __builtin_amdgcn_fmed3f(d, d1, d2);
      d1 = __builtin_amdgcn_fmed3f(d, d0, d1);
      d0 = fminf(d, d0);
    }
    float* cd = (float*)smem + (slice*32 + row)*8;
    cd[0]=d0; cd[1]=d1; cd[2]=d2;
    ((int*)cd)[4]=i0; ((int*)cd)[5]=i1; ((int*)cd)[6]=i2;
  }
  __syncthreads();
  if (t < TM) {                                // merge 8 slices, j-ascending (ties->ref)
    float d0=3.4e38f,d1=3.4e38f,d2=3.4e38f; int i0=0,i1=0,i2=0;
    for (int p=0;p<8;++p){
      const float* cd = (const float*)smem + (p*32 + t)*8;
      for (int c=0;c<3;++c){
        float d = cd[c]; int ii = ((const int*)cd)[4+c];
        if (d < d2) {
          if (d < d1) { d2=d1; i2=i1;
            if (d < d0) { d1=d0; i1=i0; d0=d; i0=ii; } else { d1=d; i1=ii; }
          } else { d2=d; i2=ii; }
        }
      }
    }
    d0=fmaxf(d0,EPSD); d1=fmaxf(d1,EPSD); d2=fmaxf(d2,EPSD);
    float w0=1.f/d0, w1=1.f/d1, w2=1.f/d2, inv=1.f/(w0+w1+w2);
    s_w[t][0]=w0*inv; s_w[t][1]=w1*inv; s_w[t][2]=w2*inv;
    s_idx[t][0]=i0; s_idx[t][1]=i1; s_idx[t][2]=i2;
  }
  __syncthreads();

  // ===== Phase B =====
  const int rr = t >> 3, qq = t & 7;           // X build: 8 thr/row, 8 k each
  const float w0_=s_w[rr][0], w1_=s_w[rr][1], w2_=s_w[rr][2];
  const int g0=s_idx[rr][0], g1=s_idx[rr][1], g2=s_idx[rr][2];
  const char* wsW1 = ws + WS_W1;
  const char* wsW2 = ws + WS_W2;
  const float* p2b = p2 + (size_t)b*N2*F2;
  const float* p1r = p1 + ((size_t)b*N1 + row0 + rr)*F1;

  auto issueAny = [&](int kcg, float4* g){
    if (kcg < 4) {
      const int k0 = kcg*64 + qq*8;
      const float4* q0 = (const float4*)(p2b + (size_t)g0*F2 + k0);
      const float4* q1 = (const float4*)(p2b + (size_t)g1*F2 + k0);
      const float4* q2 = (const float4*)(p2b + (size_t)g2*F2 + k0);
      g[0]=q0[0]; g[1]=q0[1]; g[2]=q1[0]; g[3]=q1[1]; g[4]=q2[0]; g[5]=q2[1];
    } else {
      const float4* q = (const float4*)(p1r + (kcg*64 + qq*8 - F2));
      g[0]=q[0]; g[1]=q[1];
    }
  };
  auto writeAny = [&](int kcg, const float4* g){
    float v[8];
    if (kcg < 4) {
      #pragma unroll
      for (int p=0;p<2;++p){
        v[4*p+0] = fmaf(w2_, g[4+p].x, fmaf(w1_, g[2+p].x, w0_*g[p].x));
        v[4*p+1] = fmaf(w2_, g[4+p].y, fmaf(w1_, g[2+p].y, w0_*g[p].y));
        v[4*p+2] = fmaf(w2_, g[4+p].z, fmaf(w1_, g[2+p].z, w0_*g[p].z));
        v[4*p+3] = fmaf(w2_, g[4+p].w, fmaf(w1_, g[2+p].w, w0_*g[p].w));
      }
    } else {
      #pragma unroll
      for (int p=0;p<2;++p){
        v[4*p+0]=g[p].x; v[4*p+1]=g[p].y; v[4*p+2]=g[p].z; v[4*p+3]=g[p].w;
      }
    }
    unsigned u[4];
    #pragma unroll
    for (int p=0;p<4;++p)
      u[p] = (unsigned)f2bf(v[2*p]) | ((unsigned)f2bf(v[2*p+1])<<16);
    *(uint4*)(smem + rr*XT_STRIDE + (kcg*8 + qq)*16) = make_uint4(u[0],u[1],u[2],u[3]);
  };
  auto loadW = [&](const char* base, int s, bf16x8* dst){  // coalesced 1KB frags
    #pragma unroll
    for (int nt=0;nt<4;++nt)
      dst[nt] = *(const bf16x8*)(base + ((s*16 + nq*4 + nt)<<10) + lane*16);
  };
  auto gemmStep = [&](int slot4, const bf16x8* bw, f32x4 (&ac)[2][4],
                      const char* Ab, int stride){
    bf16x8 af[2];
    #pragma unroll
    for (int mt=0;mt<2;++mt)
      af[mt] = *(const bf16x8*)(Ab + (mt*16+lrow)*stride + (slot4+lg)*16);
    #pragma unroll
    for (int mt=0;mt<2;++mt)
      #pragma unroll
      for (int nt=0;nt<4;++nt)
        ac[mt][nt] = __builtin_amdgcn_mfma_f32_16x16x32_bf16(af[mt], bw[nt], ac[mt][nt], 0,0,0);
  };

  f32x4 acc[2][4];
  #pragma unroll
  for (int mt=0;mt<2;++mt)
    #pragma unroll
    for (int nt=0;nt<4;++nt) acc[mt][nt] = (f32x4){0.f,0.f,0.f,0.f};

  // ---- W steps 0,1 prefetch FIRST (L2 latency hides under the X build) ----
  bf16x8 bwA[4], bwB[4];
  loadW(wsW1, 0, bwA);
  loadW(wsW1, 1, bwB);

  // ---- build full X tile (32 x 384), depth-2 gather pipeline ----
  float4 ga[6], gb[6];
  issueAny(0, ga); issueAny(1, gb);
  writeAny(0, ga); issueAny(2, ga);
  writeAny(1, gb); issueAny(3, gb);
  writeAny(2, ga); issueAny(4, ga);
  writeAny(3, gb); issueAny(5, gb);
  writeAny(4, ga); writeAny(5, gb);
  __syncthreads();

  // ---- GEMM1: 12 K32 steps, no internal barriers, W prefetch distance 2 ----
  #pragma unroll
  for (int u=0; u<6; ++u) {
    gemmStep((2*u)*4, bwA, acc, smem, XT_STRIDE);
    if (u<5) loadW(wsW1, 2*u+2, bwA);
    else     loadW(wsW2, 0, bwA);              // prefetch W2 step 0
    gemmStep((2*u+1)*4, bwB, acc, smem, XT_STRIDE);
    if (u<5) loadW(wsW1, 2*u+3, bwB);
    else     loadW(wsW2, 1, bwB);              // prefetch W2 step 1
  }
  __syncthreads();                             // Xt dead

  // ---- h = lrelu(acc + b1) -> LDS [32][264 shorts] ----
  {
    float bb[4];
    #pragma unroll
    for (int nt=0;nt<4;++nt) bb[nt] = b1[nq*64 + nt*16 + lrow];
    #pragma unroll
    for (int mt=0;mt<2;++mt)
      #pragma unroll
      for (int rg=0;rg<4;++rg) {
        const int row = mt*16 + lg*4 + rg;
        #pragma unroll
        for (int nt=0;nt<4;++nt) {
          const int col = nq*64 + nt*16 + lrow;
          *(short*)(smem + row*H_STRIDE + col*2) =
              (short)f2bf(lrelu(acc[mt][nt][rg] + bb[nt]));
        }
      }
  }
  __syncthreads();

  // ---- GEMM2: h(32x256) @ W2, 8 K32 steps, prefetch distance 2 ----
  f32x4 acc2[2][4];
  #pragma unroll
  for (int mt=0;mt<2;++mt)
    #pragma unroll
    for (int nt=0;nt<4;++nt) acc2[mt][nt] = (f32x4){0.f,0.f,0.f,0.f};
  #pragma unroll
  for (int u=0; u<4; ++u) {
    gemmStep((2*u)*4, bwA, acc2, smem, H_STRIDE);
    if (u<3) loadW(wsW2, 2*u+2, bwA);
    gemmStep((2*u+1)*4, bwB, acc2, smem, H_STRIDE);
    if (u<3) loadW(wsW2, 2*u+3, bwB);
  }

  // ---- epilogue ----
  {
    float bb[4];
    #pragma unroll
    for (int nt=0;nt<4;++nt) bb[nt] = b2[nq*64 + nt*16 + lrow];
    float* ob = out + ((size_t)b*N1 + row0) * H2;
    #pragma unroll
    for (int mt=0;mt<2;++mt)
      #pragma unroll
      for (int rg=0;rg<4;++rg) {
        const int row = mt*16 + lg*4 + rg;
        #pragma unroll
        for (int nt=0;nt<4;++nt) {
          const int col = nq*64 + nt*16 + lrow;
          ob[(size_t)row*H2 + col] = lrelu(acc2[mt][nt][rg] + bb[nt]);
        }
      }
  }
}

extern "C" void kernel_launch(void* const* d_in, const int* in_sizes, int n_in,
                              void* d_out, int out_size, void* d_ws, size_t ws_size,
                              hipStream_t stream) {
  const float* xyz1    = (const float*)d_in[0];
  const float* xyz2    = (const float*)d_in[1];
  const float* points1 = (const float*)d_in[2];
  const float* points2 = (const float*)d_in[3];
  const float* W1      = (const float*)d_in[4];
  const float* b1      = (const float*)d_in[5];
  const float* W2      = (const float*)d_in[6];
  const float* b2      = (const float*)d_in[7];
  float* out = (float*)d_out;

  hipLaunchKernelGGL(transform_w, dim3(112), dim3(256), 0, stream,
                     W1, W2, xyz2, (char*)d_ws);
  hipLaunchKernelGGL(fp_mfma, dim3(NB * (N1 / TM)), dim3(256), 0, stream,
                     xyz1, points1, points2, (const char*)d_ws, b1, b2, out);
}